// Round 15
// baseline (103.627 us; speedup 1.0000x reference)
//
#include <hip/hip_runtime.h>
#include <cstdint>

// ---------------------------------------------------------------------------
// MXFP linear w/ MSD(NAF) truncation — round 15: LUT main.
//
// Math (validated R1/R4/R9/R13/R14, absmax 2^-7):
//   contribution = r(effc, mx, mw) * fxs * fws, summed over k, + bias;
//   effc = clamp(budget - di, 0, 10), budget = 14 - emax + floor(lx+lw),
//   r = NAF-truncation of 2*mx*mw keeping effc digits (table below).
//   PROVED: intra e_max_block == 0 always -> di = min(-e,63), no shfl.
//
// R15 vs R14 (measured: R9/R10/R14 mains — three different ILP structures —
// ALL total 98-100us => main stuck at ~35us regardless of latency structure
// => instruction-bound, not latency-bound; 15-op chain x 67M = 12.8us floor):
//   1. main: r via LDS lookup table lut[2816] (11KB), built per block.
//      Per product: sub, med3(clamp), add, lshl_add, ds_read_b32, mul, fmac
//      = 6 VALU + 1 LDS (byte index prefolded: prep stores mx<<6, mw<<2).
//      New floor ~5.8us.
//   2. 4 outs/wave, grid 2048, launch_bounds(256,8): 8 blocks/CU,
//      8 waves/SIMD (2x latency hiding). LDS 15.4KB/block -> 123KB/CU ok.
// ---------------------------------------------------------------------------

#define NN 128
#define KF 1024
#define OF 512
#define NB 32
#define KS 32           // K-split: 32 chunks x 32 k (exactly one block)

// ws layout (16B-aligned offsets):
//   xaP   @ 0        1 MB   (512 kp x 128 n x 16B; 2 k-elems per uint4)
//   wB    @ 1048576  4 MB   (512 o x 1024 k x 8B: fws bits, mw<<2)
//   lxT   @ 5242880  16 KB  (32 b x 128 n)
//   lw    @ 5259264  64 KB  (512 o x 32 b)
//   emaxT @ 5324800  256 KB (512 o x 128 n)
//   part  @ 5580800  8 MB   (32 s x 512 o x 128 n f32)

__global__ __launch_bounds__(256) void prep_kernel(
    const float* __restrict__ x, const float* __restrict__ w,
    uint2* __restrict__ xaP2, uint2* __restrict__ wB,
    float* __restrict__ lxT, float* __restrict__ lw) {
  int bid = blockIdx.x;
  int tid = (int)threadIdx.x;
  bool is_x = bid < 512;
  int eid = is_x ? bid * 256 + tid : (bid - 512) * 256 + tid;
  float v = is_x ? x[eid] : w[eid];
  float a = fabsf(v);
  float m = a;
  #pragma unroll
  for (int s = 1; s < 32; s <<= 1) m = fmaxf(m, __shfl_xor(m, s, 32));
  float scale = fmaxf(m, 1e-30f);
  float xn = v / scale;                       // IEEE-exact division
  unsigned nb_ = __float_as_uint(xn);
  unsigned ab = nb_ & 0x7fffffffu;
  bool zz = ab < 0x00800000u;                 // zero (subnormals impossible)
  int e = (int)(ab >> 23) - 127;
  // mantissa in [1,2) exactly; mi = round-half-even(mant*8) in [8,16]
  float am = __uint_as_float((ab & 0x007fffffu) | 0x3f800000u);
  int mi = (int)rintf(am * 8.0f);
  if (mi == 16) { mi = 8; ++e; }              // renormalize
  if (zz) mi = 0;
  unsigned sgn = nb_ & 0x80000000u;
  unsigned sb = __float_as_uint(scale);
  if (is_x) {
    // e_max_block == 0 always -> di = -e (zeros: di=63 -> effc=0 -> r=0).
    int di = zz ? 63 : min(-e, 63);
    unsigned fb = zz ? 0u : ((sb + (((unsigned)e) << 23)) | sgn);
    unsigned meta = ((unsigned)mi << 6) | ((unsigned)di << 12);
    int k = eid & 1023, n = eid >> 10;
    xaP2[((k >> 1) * NN + n) * 2 + (k & 1)] = make_uint2(fb, meta);
    if ((tid & 31) == 0) lxT[(k >> 5) * NN + n] = log2f(scale);
  } else {
    unsigned fb = zz ? 0u : ((sb + (((unsigned)(e - 7)) << 23)) | sgn);
    wB[eid] = make_uint2(fb, (unsigned)(mi << 2));
    int o = eid >> 10, k = eid & 1023;
    if ((tid & 31) == 0) lw[o * NB + (k >> 5)] = log2f(scale);
  }
}

__global__ __launch_bounds__(256) void emax_kernel(
    const float* __restrict__ lxT, const float* __restrict__ lw,
    float* __restrict__ emaxT) {
  int gid = blockIdx.x * 256 + (int)threadIdx.x;   // 65536
  int n = gid & (NN - 1), o = gid >> 7;
  float m = -1e30f;
  #pragma unroll
  for (int b = 0; b < NB; ++b)
    m = fmaxf(m, floorf(lxT[b * NN + n] + lw[o * NB + b]));
  emaxT[o * NN + n] = m;
}

// grid 2048 = s(32 K-chunks) x og(32 groups of 16 outs) x ng(2);
// 256 thr / 4 waves; wave w4 owns 4 outs. 8 blocks/CU, 8 waves/SIMD.
__global__ __launch_bounds__(256, 8) void main_kernel(
    const uint4* __restrict__ xaP, const uint2* __restrict__ wB,
    const float* __restrict__ lxT, const float* __restrict__ lw,
    const float* __restrict__ emaxT, float* __restrict__ part) {
  __shared__ float lut[2816];                     // [effc<<8 | mx<<4 | mw]
  __shared__ __align__(16) uint2 tile[16 * 32];   // 16 outs x 32 k, 4KB
  int bid = blockIdx.x;
  int s   = bid & 31;
  int og  = (bid >> 5) & 31;
  int ng  = bid >> 10;
  int tid = (int)threadIdx.x, lane = tid & 63, w4 = tid >> 6;
  int o_base = og * 16;
  int k0 = s * 32;
  int n = ng * 64 + lane;

  // build NAF-truncation table: 11 entries/thread, once per block
  #pragma unroll 1
  for (int i = tid; i < 2816; i += 256) {
    int effc = i >> 8, mx = (i >> 4) & 15, mw = i & 15;
    int p  = mx * mw;
    int s3 = 3 * p;
    unsigned cx = (unsigned)(s3 ^ p);
    int wd = 32 - __clz(cx);                  // __clz(0)=32 -> wd=0
    int drop = max(wd - effc, 0);
    unsigned kc = (0xFFFFFFFFu << drop) & cx;
    int r = (int)((unsigned)s3 & kc) - (int)((unsigned)p & kc);
    lut[i] = (float)r;
  }
  // stage 16 outs x 32 k of wB (4KB): 16 threads/row x 1 uint4
  {
    int r = tid >> 4, c = tid & 15;
    const uint4* src = reinterpret_cast<const uint4*>(&wB[(o_base + r) * KF + k0]);
    reinterpret_cast<uint4*>(&tile[r * 32])[c] = src[c];
  }

  int ow = o_base + w4 * 4;
  float lxv = lxT[s * NN + n];
  float acc[4];
  int bv[4];
  #pragma unroll
  for (int j = 0; j < 4; ++j) {
    acc[j] = 0.f;
    float em = emaxT[(ow + j) * NN + n];
    bv[j] = (int)(14.0f - em + floorf(lxv + lw[(ow + j) * NB + s]));
  }
  __syncthreads();

  const uint4* xaRow = &xaP[(size_t)(k0 >> 1) * NN + n];
  const char* lutB = (const char*)lut;
#define LDT(j, g) (*reinterpret_cast<const uint4*>(&tile[(w4 * 4 + (j)) * 32 + 2 * (g)]))
  // one product: effc=med3(bv-di,0,10); byte idx=(effc<<10)+mx64+mw4;
  // lut read; acc += lut * (fxs*fws).  6 VALU + 1 ds_read.
#define PROD(J, T, MX64, DI, FXS, HI)                                      \
  {                                                                        \
    int e_ = min(max(bv[J] - (DI), 0), 10);                                \
    int bx_ = (e_ << 10) + ((MX64) + (int)((HI) ? (T).w : (T).y));         \
    float lv_ = *(const float*)(lutB + bx_);                               \
    float f_ = (FXS) * __uint_as_float((HI) ? (T).z : (T).x);              \
    acc[J] = fmaf(lv_, f_, acc[J]);                                        \
  }

  uint4 xa_ = xaRow[0];
  #pragma unroll 2
  for (int g = 0; g < 16; ++g) {
    // prefetch next group's xa (g=15 reads past xaP end: lands in wB, in ws)
    uint4 xn_ = xaRow[(size_t)(g + 1) * NN];
    int mx64_0 = (int)(xa_.y & 0x3C0u), di0 = (int)(xa_.y >> 12);
    int mx64_1 = (int)(xa_.w & 0x3C0u), di1 = (int)(xa_.w >> 12);
    float fx0 = __uint_as_float(xa_.x), fx1 = __uint_as_float(xa_.z);
    uint4 t0 = LDT(0, g), t1 = LDT(1, g), t2 = LDT(2, g), t3 = LDT(3, g);
    PROD(0, t0, mx64_0, di0, fx0, 0); PROD(0, t0, mx64_1, di1, fx1, 1);
    PROD(1, t1, mx64_0, di0, fx0, 0); PROD(1, t1, mx64_1, di1, fx1, 1);
    PROD(2, t2, mx64_0, di0, fx0, 0); PROD(2, t2, mx64_1, di1, fx1, 1);
    PROD(3, t3, mx64_0, di0, fx0, 0); PROD(3, t3, mx64_1, di1, fx1, 1);
    xa_ = xn_;
  }

  #pragma unroll
  for (int j = 0; j < 4; ++j)
    part[((size_t)(s * OF) + ow + j) * NN + n] = acc[j];
#undef PROD
#undef LDT
}

__global__ __launch_bounds__(256) void reduce_kernel(
    const float* __restrict__ part, const float* __restrict__ bias,
    float* __restrict__ out) {
  int gid = blockIdx.x * 256 + (int)threadIdx.x;   // 65536
  int n = gid & (NN - 1), o = gid >> 7;
  float sum = bias[o];
  #pragma unroll
  for (int c = 0; c < KS; ++c) sum += part[((size_t)c * OF + o) * NN + n];
  out[n * OF + o] = sum;
}

extern "C" void kernel_launch(void* const* d_in, const int* in_sizes, int n_in,
                              void* d_out, int out_size, void* d_ws, size_t ws_size,
                              hipStream_t stream) {
  const float* x    = (const float*)d_in[0];
  const float* w    = (const float*)d_in[1];
  const float* bias = (const float*)d_in[2];
  float* out = (float*)d_out;
  char* ws = (char*)d_ws;
  uint2* xaP2  = (uint2*)(ws);
  uint4* xaP   = (uint4*)(ws);
  uint2* wB    = (uint2*)(ws + 1048576);
  float* lxT   = (float*)(ws + 5242880);
  float* lw    = (float*)(ws + 5259264);
  float* emaxT = (float*)(ws + 5324800);
  float* part  = (float*)(ws + 5580800);

  prep_kernel<<<2560, 256, 0, stream>>>(x, w, xaP2, wB, lxT, lw);
  emax_kernel<<<256, 256, 0, stream>>>(lxT, lw, emaxT);
  main_kernel<<<2048, 256, 0, stream>>>(xaP, wB, lxT, lw, emaxT, part);
  reduce_kernel<<<256, 256, 0, stream>>>(part, bias, out);
}